// Round 6
// baseline (229.821 us; speedup 1.0000x reference)
//
#include <hip/hip_runtime.h>
#include <math.h>

#define B_ 16
#define M_ 2048
#define C_ 128

using f4 = float4;
typedef __attribute__((ext_vector_type(8))) short bf16x8;
typedef __attribute__((ext_vector_type(16))) float f32x16;

#define GLOAD16(gsrc, ldst) __builtin_amdgcn_global_load_lds( \
    (const __attribute__((address_space(1))) unsigned int*)(gsrc), \
    (__attribute__((address_space(3))) unsigned int*)(ldst), 16, 0, 0)

// round-to-nearest-even f32 -> bf16 bits
__device__ inline unsigned short bfr(float f) {
    unsigned int u = __float_as_uint(f);
    return (unsigned short)((u + 0x7FFFu + ((u >> 16) & 1u)) >> 16);
}

// ---------------------------------------------------------------- x -> xhi, xlo (bf16), sq
__global__ __launch_bounds__(256) void prep_kernel(const float* __restrict__ x,
                                                   uint2* __restrict__ xhi,
                                                   uint2* __restrict__ xlo,
                                                   float* __restrict__ sq) {
    int wid = threadIdx.x >> 6, lane = threadIdx.x & 63;
    int l31 = lane & 31, l5 = lane >> 5;
    int row = blockIdx.x * 8 + wid * 2 + l5;
    f4 v = ((const f4*)(x + (size_t)row * C_))[l31];
    unsigned short h0 = bfr(v.x), h1 = bfr(v.y), h2 = bfr(v.z), h3 = bfr(v.w);
    float r0 = v.x - __uint_as_float((unsigned)h0 << 16);
    float r1 = v.y - __uint_as_float((unsigned)h1 << 16);
    float r2 = v.z - __uint_as_float((unsigned)h2 << 16);
    float r3 = v.w - __uint_as_float((unsigned)h3 << 16);
    unsigned short l0 = bfr(r0), l1 = bfr(r1), l2 = bfr(r2), l3 = bfr(r3);
    uint2 hp, lp;
    hp.x = (unsigned)h0 | ((unsigned)h1 << 16);
    hp.y = (unsigned)h2 | ((unsigned)h3 << 16);
    lp.x = (unsigned)l0 | ((unsigned)l1 << 16);
    lp.y = (unsigned)l2 | ((unsigned)l3 << 16);
    xhi[(size_t)row * 32 + l31] = hp;          // 256B per row
    xlo[(size_t)row * 32 + l31] = lp;
    float dot = v.x * v.x + v.y * v.y + v.z * v.z + v.w * v.w;
    #pragma unroll
    for (int m = 1; m < 32; m <<= 1) dot += __shfl_xor(dot, m);
    if (l31 == 0) sq[row] = dot;
}

// ---------------------------------------------------------------- persistent-panel MFMA Gram
// 64-col j-steps, 4-buffer LDS ring, prefetch depth 3, counted vmcnt (never 0 mid-loop).
// Waves: 4 row-blocks (32 rows) x 2 col-blocks (32 cols). A panel in registers.
// MODE 0: hi*hi -> off-diag dist sum; grid 512 (j-range split in 2), 2 blocks/CU.
// MODE 1: hi*hi+hi*lo+lo*hi -> rho direct; grid 256.
template <int MODE>
__global__ __launch_bounds__(512, 2) void gram_mfma(
    const char* __restrict__ xhi, const char* __restrict__ xlo,
    const float* __restrict__ sq, const float* __restrict__ invh,
    double* __restrict__ off_part, float* __restrict__ rho) {
    constexpr int TBUF = (MODE == 1) ? 32768 : 16384;  // per ring buffer (hi[+lo] of 64 cols)
    constexpr int NS   = (MODE == 1) ? 32 : 16;        // 64-col steps per block
    constexpr int SQI  = (MODE == 1) ? 8 : 4;          // sqj slab gload insts (1KB each)
    __shared__ __align__(16) char lds[4 * TBUF];
    __shared__ __align__(16) float sqjs[NS * 64];
    __shared__ __align__(8)  float scr[256];
    __shared__ float sqs[128];
    int tid = threadIdx.x, lane = tid & 63, wid = tid >> 6;
    int l31 = lane & 31, l5 = lane >> 5;
    int wr = wid >> 1, wc = wid & 1;                   // 32-row block, 32-col block
    int bid = blockIdx.x;
    int b, ip, jstart;
    if (MODE == 1) {
        int swz = (bid & 7) * 32 + (bid >> 3);         // bijective XCD swizzle (256=8*32)
        b = swz >> 4; ip = swz & 15; jstart = 0;
    } else {
        int swz = (bid & 7) * 64 + (bid >> 3);         // bijective XCD swizzle (512=8*64)
        b = swz >> 5; ip = (swz >> 1) & 15; jstart = (swz & 1) * 1024;
    }
    const char* hbase = xhi + (size_t)b * M_ * 256;
    const char* lbase = xlo + (size_t)b * M_ * 256;

    // stage a 64-row (16KB) tile: 16 insts, 2 per wave; swizzled source, linear dest
    auto stage16 = [&](const char* src, char* dst) {
        #pragma unroll
        for (int q = 0; q < 2; ++q) {
            int inst = wid * 2 + q;
            int row  = inst * 4 + (lane >> 4);
            int ch   = (lane & 15) ^ (row & 15);
            GLOAD16(src + row * 256 + ch * 16, dst + inst * 1024);
        }
    };
    // stage B step tile s into ring buffer s&3
    auto stageB = [&](int s) {
        char* dst = lds + (size_t)(s & 3) * TBUF;
        const char* hs = hbase + (size_t)(jstart + s * 64) * 256;
        stage16(hs, dst);
        if (MODE == 1) stage16(lbase + (size_t)(jstart + s * 64) * 256, dst + 16384);
    };
    // stage A 128-row 32KB region: 32 insts, 4 per wave
    auto stageA = [&](const char* src, char* dst) {
        #pragma unroll
        for (int q = 0; q < 4; ++q) {
            int inst = wid * 4 + q;
            int row  = inst * 4 + (lane >> 4);
            int ch   = (lane & 15) ^ (row & 15);
            GLOAD16(src + row * 256 + ch * 16, dst + inst * 1024);
        }
    };

    // ---- prologue: sqj slab + A panel -> LDS -> registers
    if (wid < SQI)
        GLOAD16((const char*)(sq + (size_t)b * M_ + jstart) + wid * 1024 + lane * 16,
                (char*)sqjs + wid * 1024);
    stageA(hbase + (size_t)ip * 32768, lds);                       // A hi -> [0,32K)
    if (MODE == 1) stageA(lbase + (size_t)ip * 32768, lds + 32768); // A lo -> [32K,64K)
    if (MODE == 0 && tid < 128) sqs[tid] = sq[b * M_ + ip * 128 + tid];
    asm volatile("s_waitcnt vmcnt(0)" ::: "memory");
    __syncthreads();
    bf16x8 ahi[8], alo[8];
    {
        int row = wr * 32 + l31;
        #pragma unroll
        for (int ks = 0; ks < 8; ++ks) {
            int ch = ((ks << 1) | l5) ^ (row & 15);
            ahi[ks] = *(const bf16x8*)(lds + row * 256 + ch * 16);
            if (MODE == 1)
                alo[ks] = *(const bf16x8*)(lds + 32768 + row * 256 + ch * 16);
        }
    }
    __syncthreads();                       // all waves' A-frag reads done -> ring may overwrite
    stageB(0); stageB(1); stageB(2);       // prefetch depth 3

    float svh = 0.f;
    if (MODE == 1) svh = invh[b] * 1.4426950408889634f;   // s * log2(e)
    float c2 = 2.f * svh;
    float rs[16];
    #pragma unroll
    for (int rg = 0; rg < 16; ++rg) rs[rg] = 0.f;
    float part = 0.f;

    #pragma unroll 1
    for (int s = 0; s < NS; ++s) {
        // boundary: wait own stage-s loads done (counted: 2 stages may stay in flight),
        // own prior ds_reads done, then barrier => tile s resident for all waves AND
        // buf[(s+3)&3] == buf[(s-1)&3] free to overwrite.
        if constexpr (MODE == 1) {
            if (s < NS - 2)       asm volatile("s_waitcnt vmcnt(8)" ::: "memory");
            else if (s == NS - 2) asm volatile("s_waitcnt vmcnt(4)" ::: "memory");
            else                  asm volatile("s_waitcnt vmcnt(0)" ::: "memory");
        } else {
            if (s < NS - 2)       asm volatile("s_waitcnt vmcnt(4)" ::: "memory");
            else if (s == NS - 2) asm volatile("s_waitcnt vmcnt(2)" ::: "memory");
            else                  asm volatile("s_waitcnt vmcnt(0)" ::: "memory");
        }
        asm volatile("s_waitcnt lgkmcnt(0)" ::: "memory");
        __builtin_amdgcn_s_barrier();
        __builtin_amdgcn_sched_barrier(0);
        if (s + 3 < NS) stageB(s + 3);
        const char* cur = lds + (size_t)(s & 3) * TBUF;
        float sqj = sqjs[s * 64 + wc * 32 + l31];
        int brow = wc * 32 + l31;
        f32x16 accA = {}, accB = {};       // two independent dep chains
        #pragma unroll
        for (int ks = 0; ks < 8; ++ks) {
            int ch = ((ks << 1) | l5) ^ (brow & 15);
            bf16x8 bh = *(const bf16x8*)(cur + brow * 256 + ch * 16);
            __builtin_amdgcn_s_setprio(1);
            if (ks & 1) accB = __builtin_amdgcn_mfma_f32_32x32x16_bf16(ahi[ks], bh, accB, 0, 0, 0);
            else        accA = __builtin_amdgcn_mfma_f32_32x32x16_bf16(ahi[ks], bh, accA, 0, 0, 0);
            if (MODE == 1) {
                bf16x8 bl = *(const bf16x8*)(cur + 16384 + brow * 256 + ch * 16);
                accB = __builtin_amdgcn_mfma_f32_32x32x16_bf16(alo[ks], bh, accB, 0, 0, 0);
                accA = __builtin_amdgcn_mfma_f32_32x32x16_bf16(ahi[ks], bl, accA, 0, 0, 0);
            }
            __builtin_amdgcn_s_setprio(0);
        }
        if (MODE == 1) {
            float m = -sqj * svh;
            #pragma unroll
            for (int rg = 0; rg < 16; ++rg)
                rs[rg] += exp2f(fmaf(accA[rg] + accB[rg], c2, m));
        } else {
            #pragma unroll
            for (int rg = 0; rg < 16; ++rg) {
                int rl = (rg & 3) + ((rg >> 2) << 3) + (l5 << 2);
                float si = sqs[wr * 32 + rl];
                float d  = si + sqj - 2.f * (accA[rg] + accB[rg]);
                float sd = sqrtf(fmaxf(d, 1e-12f));
                if ((ip * 128 + wr * 32 + rl) == (jstart + s * 64 + wc * 32 + l31)) sd = 0.f;
                part += sd;
            }
        }
    }

    if (MODE == 1) {
        #pragma unroll
        for (int rg = 0; rg < 16; ++rg) {
            float v = rs[rg];
            #pragma unroll
            for (int m = 1; m < 32; m <<= 1) v += __shfl_xor(v, m);
            rs[rg] = v;
        }
        __syncthreads();
        if (l31 == 0) {
            #pragma unroll
            for (int rg = 0; rg < 16; ++rg) {
                int r0 = wr * 32 + (rg & 3) + ((rg >> 2) << 3) + (l5 << 2);
                scr[wc * 128 + r0] = rs[rg];
            }
        }
        __syncthreads();
        if (tid < 128) {
            int pt = b * M_ + ip * 128 + tid;
            rho[pt] = exp2f(-sq[pt] * svh) * (scr[tid] + scr[128 + tid]);
        }
    } else {
        #pragma unroll
        for (int m = 1; m < 64; m <<= 1) part += __shfl_xor(part, m);
        __syncthreads();
        double* dscr = (double*)scr;
        if (lane == 0) dscr[wid] = (double)part;
        __syncthreads();
        if (tid == 0) {
            double t = 0.0;
            #pragma unroll
            for (int w = 0; w < 8; ++w) t += dscr[w];
            off_part[b * 32 + ip * 2 + (jstart >> 10)] = t;
        }
    }
}

// ---------------------------------------------------------------- fused: invh (block 0) + g/dvs (block 1)
__global__ __launch_bounds__(256) void small_kernel(const double* __restrict__ op,
                                                    float* __restrict__ invh,
                                                    float* __restrict__ g,
                                                    float* __restrict__ dvs) {
    int tid = threadIdx.x;
    if (blockIdx.x == 0) {
        int b = tid >> 4, k = tid & 15;
        double v = op[b * 32 + k] + op[b * 32 + 16 + k];
        #pragma unroll
        for (int m = 1; m < 16; m <<= 1) v += __shfl_xor(v, m);
        if (k == 0) {
            double h = v / ((double)M_ * (double)(M_ - 1));
            h = h > 1e-6 ? h : 1e-6;
            invh[b] = (float)(1.0 / (2.0 * h * h));
        }
    } else {
        __shared__ double w[256];
        double loc = 0.0;
        #pragma unroll
        for (int q = 0; q < 8; ++q) loc += 1.0 / (double)(M_ - (tid * 8 + q));
        w[tid] = loc; __syncthreads();
        for (int o = 1; o < 256; o <<= 1) {
            double v = (tid >= o) ? w[tid - o] : 0.0;
            __syncthreads();
            w[tid] += v;
            __syncthreads();
        }
        double acc = (tid > 0) ? w[tid - 1] : 0.0;
        #pragma unroll
        for (int q = 0; q < 8; ++q) {
            int t = tid * 8 + q;
            acc += 1.0 / (double)(M_ - t);
            g[t]   = (float)acc;
            dvs[t] = (float)(1.0 / sqrt((double)(t + 1)));
        }
    }
}

// ---------------------------------------------------------------- rank + scatter permutation
__global__ __launch_bounds__(128) void rank_kernel(const float* __restrict__ rho,
                                                   int* __restrict__ perm) {
    int b = blockIdx.y;
    int i = blockIdx.x * 128 + threadIdx.x;
    __shared__ float r[M_];
    const float* rb = rho + b * M_;
    for (int t = threadIdx.x; t < M_; t += 128) r[t] = rb[t];
    __syncthreads();
    float rv = r[i];
    int cnt = 0;
    #pragma unroll 4
    for (int j = 0; j < M_; ++j) {
        float o = r[j];
        cnt += (o < rv || (o == rv && j < i)) ? 1 : 0;
    }
    perm[b * M_ + cnt] = i;
}

// ---------------------------------------------------------------- per-chunk partial sums (64-pt chunks)
__global__ __launch_bounds__(128) void scan_chunk(
    const float* __restrict__ x, const int* __restrict__ perm,
    const float* __restrict__ g, const float* __restrict__ dvs,
    double* __restrict__ chunkU, double* __restrict__ chunkGU) {
    int b = blockIdx.x, ch = blockIdx.y, c = threadIdx.x;
    __shared__ int   pidx[64];
    __shared__ float gl[64], dl[64];
    int t0 = ch * 64;
    if (c < 64) {
        pidx[c] = perm[b * M_ + t0 + c];
        gl[c]   = g[t0 + c];
        dl[c]   = dvs[t0 + c];
    }
    __syncthreads();
    const float* xb = x + (size_t)b * M_ * C_;
    double sU = 0.0, sGU = 0.0;
    #pragma unroll 4
    for (int tt = 0; tt < 64; ++tt) {
        double u = (double)xb[(size_t)pidx[tt] * C_ + c] * (double)dl[tt];
        sU  += u;
        sGU += (double)gl[tt] * u;
    }
    chunkU [(size_t)(b * 32 + ch) * 128 + c] = sU;
    chunkGU[(size_t)(b * 32 + ch) * 128 + c] = sGU;
}

// ---------------------------------------------------------------- y via two prefix scans
__global__ __launch_bounds__(128) void scan_final(
    const float* __restrict__ x, const int* __restrict__ perm,
    const float* __restrict__ g, const float* __restrict__ dvs,
    const double* __restrict__ chunkU, const double* __restrict__ chunkGU,
    float* __restrict__ y) {
    int b = blockIdx.x, ch = blockIdx.y, c = threadIdx.x;
    __shared__ int   pidx[64];
    __shared__ float gl[64], dl[64];
    int t0 = ch * 64;
    if (c < 64) {
        pidx[c] = perm[b * M_ + t0 + c];
        gl[c]   = g[t0 + c];
        dl[c]   = dvs[t0 + c];
    }
    __syncthreads();
    double Utot = 0.0, runU = 0.0, runG = 0.0;
    #pragma unroll 4
    for (int q = 0; q < 32; ++q) {
        double cu = chunkU[(size_t)(b * 32 + q) * 128 + c];
        Utot += cu;
        if (q < ch) { runU += cu; runG += chunkGU[(size_t)(b * 32 + q) * 128 + c]; }
    }
    const float* xb = x + (size_t)b * M_ * C_;
    float*       yb = y + (size_t)b * M_ * C_;
    #pragma unroll 2
    for (int tt = 0; tt < 64; ++tt) {
        int idx = pidx[tt];
        double u  = (double)xb[(size_t)idx * C_ + c] * (double)dl[tt];
        double yv = (double)dl[tt] * ((double)gl[tt] * (Utot - runU) + runG);
        yb[(size_t)idx * C_ + c] = (float)yv;
        runU += u;
        runG += (double)gl[tt] * u;
    }
}

// ---------------------------------------------------------------- out = SiLU(y @ W^T), in-place
__global__ __launch_bounds__(256, 2) void linear_silu(float* __restrict__ y,
                                                      const float* __restrict__ W) {
    int b = blockIdx.y, m0 = blockIdx.x * 64;
    __shared__ f4 Y4[64][32];
    __shared__ f4 W4[64][32];
    float* yb = y + ((size_t)b * M_ + m0) * C_;
    int tid = threadIdx.x;
    for (int s = tid; s < 64 * 32; s += 256) {
        int row = s >> 5, c4 = s & 31;
        Y4[row][c4 ^ (row & 31)] = ((const f4*)(yb + (size_t)row * C_))[c4];
    }
    int tx = tid & 15, ty = tid >> 4;
    for (int half = 0; half < 2; ++half) {
        __syncthreads();
        for (int s = tid; s < 64 * 32; s += 256) {
            int row = s >> 5, c4 = s & 31;
            W4[row][c4 ^ (row & 31)] = ((const f4*)(W + (size_t)(half * 64 + row) * C_))[c4];
        }
        __syncthreads();
        float acc[4][4] = {};
        #pragma unroll 4
        for (int k4 = 0; k4 < 32; ++k4) {
            f4 a[4], w[4];
            #pragma unroll
            for (int d = 0; d < 4; ++d) {
                int rm = ty + 16 * d;
                a[d] = Y4[rm][k4 ^ (rm & 31)];
                int rc = tx + 16 * d;
                w[d] = W4[rc][k4 ^ (rc & 31)];
            }
            #pragma unroll
            for (int di = 0; di < 4; ++di)
                #pragma unroll
                for (int dj = 0; dj < 4; ++dj)
                    acc[di][dj] += a[di].x * w[dj].x + a[di].y * w[dj].y +
                                   a[di].z * w[dj].z + a[di].w * w[dj].w;
        }
        #pragma unroll
        for (int di = 0; di < 4; ++di)
            #pragma unroll
            for (int dj = 0; dj < 4; ++dj) {
                int m = ty + 16 * di, co = half * 64 + tx + 16 * dj;
                float v = acc[di][dj];
                yb[(size_t)m * C_ + co] = v / (1.f + __expf(-v));
            }
    }
}

// ----------------------------------------------------------------
extern "C" void kernel_launch(void* const* d_in, const int* in_sizes, int n_in,
                              void* d_out, int out_size, void* d_ws, size_t ws_size,
                              hipStream_t stream) {
    (void)in_sizes; (void)n_in; (void)out_size; (void)ws_size;
    const float* x = (const float*)d_in[0];
    const float* W = (const float*)d_in[1];
    float* out = (float*)d_out;

    char* ws = (char*)d_ws;
    size_t o = 0;
    auto alloc = [&](size_t n) { size_t r = o; o += (n + 255) & ~(size_t)255; return r; };
    double* off_part = (double*)(ws + alloc((size_t)B_ * 32 * 8));
    float*  invh     = (float*) (ws + alloc(B_ * 4));
    float*  sqv      = (float*) (ws + alloc((size_t)B_ * M_ * 4));        // 128KB
    float*  rho      = (float*) (ws + alloc((size_t)B_ * M_ * 4));        // 128KB
    int*    perm     = (int*)   (ws + alloc((size_t)B_ * M_ * 4));        // 128KB
    float*  g        = (float*) (ws + alloc(M_ * 4));
    float*  dvs      = (float*) (ws + alloc(M_ * 4));
    double* chunkU   = (double*)(ws + alloc((size_t)B_ * 32 * C_ * 8));   // 512KB
    double* chunkGU  = (double*)(ws + alloc((size_t)B_ * 32 * C_ * 8));   // 512KB
    // xhi/xlo bf16 (8MB each) live in d_out; consumed by grams before y is written.
    char* xhi = (char*)d_out;
    char* xlo = xhi + (size_t)B_ * M_ * 256;

    prep_kernel<<<(B_ * M_) / 8, 256, 0, stream>>>(x, (uint2*)xhi, (uint2*)xlo, sqv);
    gram_mfma<0><<<512, 512, 0, stream>>>(xhi, xlo, sqv, nullptr, off_part, nullptr);
    small_kernel<<<2, 256, 0, stream>>>(off_part, invh, g, dvs);
    gram_mfma<1><<<256, 512, 0, stream>>>(xhi, xlo, sqv, invh, nullptr, rho);
    rank_kernel<<<dim3(M_ / 128, B_), 128, 0, stream>>>(rho, perm);
    scan_chunk<<<dim3(B_, 32), 128, 0, stream>>>(x, perm, g, dvs, chunkU, chunkGU);
    scan_final<<<dim3(B_, 32), 128, 0, stream>>>(x, perm, g, dvs, chunkU, chunkGU, out);
    linear_silu<<<dim3(M_ / 64, B_), 256, 0, stream>>>(out, W);
}

// Round 7
// 209.260 us; speedup vs baseline: 1.0983x; 1.0983x over previous
//
#include <hip/hip_runtime.h>
#include <math.h>

#define B_ 16
#define M_ 2048
#define C_ 128

using f4 = float4;
typedef __attribute__((ext_vector_type(8))) short bf16x8;
typedef __attribute__((ext_vector_type(16))) float f32x16;

#define GLOAD16(gsrc, ldst) __builtin_amdgcn_global_load_lds( \
    (const __attribute__((address_space(1))) unsigned int*)(gsrc), \
    (__attribute__((address_space(3))) unsigned int*)(ldst), 16, 0, 0)

// round-to-nearest-even f32 -> bf16 bits
__device__ inline unsigned short bfr(float f) {
    unsigned int u = __float_as_uint(f);
    return (unsigned short)((u + 0x7FFFu + ((u >> 16) & 1u)) >> 16);
}

// ---------------------------------------------------------------- x -> xhi (bf16), sq
__global__ __launch_bounds__(256) void prep_kernel(const float* __restrict__ x,
                                                   uint2* __restrict__ xhi,
                                                   float* __restrict__ sq) {
    int wid = threadIdx.x >> 6, lane = threadIdx.x & 63;
    int l31 = lane & 31, l5 = lane >> 5;
    int row = blockIdx.x * 8 + wid * 2 + l5;
    f4 v = ((const f4*)(x + (size_t)row * C_))[l31];
    unsigned short h0 = bfr(v.x), h1 = bfr(v.y), h2 = bfr(v.z), h3 = bfr(v.w);
    uint2 hp;
    hp.x = (unsigned)h0 | ((unsigned)h1 << 16);
    hp.y = (unsigned)h2 | ((unsigned)h3 << 16);
    xhi[(size_t)row * 32 + l31] = hp;          // 256B per row
    float dot = v.x * v.x + v.y * v.y + v.z * v.z + v.w * v.w;
    #pragma unroll
    for (int m = 1; m < 32; m <<= 1) dot += __shfl_xor(dot, m);
    if (l31 == 0) sq[row] = dot;
}

// ---------------------------------------------------------------- persistent-panel MFMA Gram (hi-only)
// 128-col j-steps, ring-4 LDS (4x32KB), prefetch depth 3, counted vmcnt (never 0 mid-loop).
// 8 waves = 2 row-blocks (64 rows) x 4 col-blocks (32 cols). A panel (hi) in registers.
// 4 parity-split acc chains per wave (same-chain MFMA separation = 32 cyc).
// MODE 0: off-diag dist sum -> off_part[b*16+ip].  MODE 1: exp-sum -> rho direct.
template <int MODE>
__global__ __launch_bounds__(512, 2) void gram_mfma(
    const char* __restrict__ xhi, const float* __restrict__ sq,
    const float* __restrict__ invh,
    double* __restrict__ off_part, float* __restrict__ rho) {
    constexpr int NS = 16;                             // 128-col steps
    __shared__ __align__(16) char lds[4 * 32768];      // ring
    __shared__ __align__(16) float sqjs[M_];           // all sq[b,:] (8KB)
    __shared__ __align__(8)  float scr[512];
    __shared__ float sqs[128];
    int tid = threadIdx.x, lane = tid & 63, wid = tid >> 6;
    int l31 = lane & 31, l5 = lane >> 5;
    int wr = wid >> 2, wc = wid & 3;                   // 64-row block, 32-col block
    int bid = blockIdx.x;
    int swz = (bid & 7) * 32 + (bid >> 3);             // bijective XCD swizzle (256=8*32)
    int b = swz >> 4, ip = swz & 15;
    const char* hbase = xhi + (size_t)b * M_ * 256;

    // stage one 32KB tile (128 rows x 256B): 32 insts, 4 per wave; swizzled src, linear dst
    auto stageT = [&](const char* src, char* dst) {
        #pragma unroll
        for (int q = 0; q < 4; ++q) {
            int inst = wid * 4 + q;
            int row  = inst * 4 + (lane >> 4);
            int ch   = (lane & 15) ^ (row & 15);
            GLOAD16(src + row * 256 + ch * 16, dst + inst * 1024);
        }
    };
    auto stageB = [&](int s) {                         // B step s -> ring buf s&3
        stageT(hbase + (size_t)s * 32768, lds + (size_t)(s & 3) * 32768);
    };

    // ---- prologue: sqj slab + A panel -> LDS -> registers
    if (wid < 8)
        GLOAD16((const char*)(sq + (size_t)b * M_) + wid * 1024 + lane * 16,
                (char*)sqjs + wid * 1024);
    stageT(hbase + (size_t)ip * 32768, lds);           // A hi into ring buf 0
    if (MODE == 0 && tid < 128) sqs[tid] = sq[b * M_ + ip * 128 + tid];
    asm volatile("s_waitcnt vmcnt(0)" ::: "memory");
    __syncthreads();
    bf16x8 ahi[2][8];
    #pragma unroll
    for (int fi = 0; fi < 2; ++fi) {
        int row = wr * 64 + fi * 32 + l31;
        #pragma unroll
        for (int ks = 0; ks < 8; ++ks) {
            int ch = ((ks << 1) | l5) ^ (row & 15);
            ahi[fi][ks] = *(const bf16x8*)(lds + row * 256 + ch * 16);
        }
    }
    asm volatile("s_waitcnt lgkmcnt(0)" ::: "memory"); // A reads done before buf0 reuse
    __builtin_amdgcn_sched_barrier(0);
    __syncthreads();
    stageB(0); stageB(1); stageB(2);                   // prefetch depth 3

    float svh = 0.f;
    if (MODE == 1) svh = invh[b] * 1.4426950408889634f;   // s * log2(e)
    float c2 = 2.f * svh;
    float rs0[16], rs1[16];
    #pragma unroll
    for (int rg = 0; rg < 16; ++rg) { rs0[rg] = 0.f; rs1[rg] = 0.f; }
    float part = 0.f;

    #pragma unroll 1
    for (int s = 0; s < NS; ++s) {
        // boundary: stage-s resident (counted: 2 stages = 8 insts may stay in flight),
        // own ds_reads drained, barrier -> ring buf (s+3)&3 free to overwrite.
        if (s < NS - 2)       asm volatile("s_waitcnt vmcnt(8)" ::: "memory");
        else if (s == NS - 2) asm volatile("s_waitcnt vmcnt(4)" ::: "memory");
        else                  asm volatile("s_waitcnt vmcnt(0)" ::: "memory");
        asm volatile("s_waitcnt lgkmcnt(0)" ::: "memory");
        __builtin_amdgcn_s_barrier();
        __builtin_amdgcn_sched_barrier(0);
        if (s + 3 < NS) stageB(s + 3);
        const char* cur = lds + (size_t)(s & 3) * 32768;
        float sqj = sqjs[s * 128 + wc * 32 + l31];
        int brow = wc * 32 + l31;
        f32x16 e0 = {}, e1 = {}, o0 = {}, o1 = {};     // 4 independent chains
        #pragma unroll
        for (int ks = 0; ks < 8; ++ks) {
            int ch = ((ks << 1) | l5) ^ (brow & 15);
            bf16x8 bh = *(const bf16x8*)(cur + brow * 256 + ch * 16);
            __builtin_amdgcn_s_setprio(1);
            if (ks & 1) {
                o0 = __builtin_amdgcn_mfma_f32_32x32x16_bf16(ahi[0][ks], bh, o0, 0, 0, 0);
                o1 = __builtin_amdgcn_mfma_f32_32x32x16_bf16(ahi[1][ks], bh, o1, 0, 0, 0);
            } else {
                e0 = __builtin_amdgcn_mfma_f32_32x32x16_bf16(ahi[0][ks], bh, e0, 0, 0, 0);
                e1 = __builtin_amdgcn_mfma_f32_32x32x16_bf16(ahi[1][ks], bh, e1, 0, 0, 0);
            }
            __builtin_amdgcn_s_setprio(0);
        }
        if (MODE == 1) {
            float m = -sqj * svh;
            #pragma unroll
            for (int rg = 0; rg < 16; ++rg) {
                rs0[rg] += exp2f(fmaf(e0[rg] + o0[rg], c2, m));
                rs1[rg] += exp2f(fmaf(e1[rg] + o1[rg], c2, m));
            }
        } else {
            #pragma unroll
            for (int rg = 0; rg < 16; ++rg) {
                int rl = (rg & 3) + ((rg >> 2) << 3) + (l5 << 2);
                float d0 = sqs[wr * 64 + rl]      + sqj - 2.f * (e0[rg] + o0[rg]);
                float d1 = sqs[wr * 64 + 32 + rl] + sqj - 2.f * (e1[rg] + o1[rg]);
                float s0 = sqrtf(fmaxf(d0, 1e-12f));
                float s1 = sqrtf(fmaxf(d1, 1e-12f));
                if (s == ip) {
                    int colt = wc * 32 + l31;
                    if ((wr * 64 + rl) == colt)      s0 = 0.f;
                    if ((wr * 64 + 32 + rl) == colt) s1 = 0.f;
                }
                part += s0 + s1;
            }
        }
    }

    if (MODE == 1) {
        #pragma unroll
        for (int rg = 0; rg < 16; ++rg) {
            float v0 = rs0[rg], v1 = rs1[rg];
            #pragma unroll
            for (int m = 1; m < 32; m <<= 1) { v0 += __shfl_xor(v0, m); v1 += __shfl_xor(v1, m); }
            rs0[rg] = v0; rs1[rg] = v1;
        }
        __syncthreads();
        if (l31 == 0) {
            #pragma unroll
            for (int rg = 0; rg < 16; ++rg) {
                int r0 = wr * 64 + (rg & 3) + ((rg >> 2) << 3) + (l5 << 2);
                scr[wc * 128 + r0]      = rs0[rg];
                scr[wc * 128 + r0 + 32] = rs1[rg];
            }
        }
        __syncthreads();
        if (tid < 128) {
            int pt = b * M_ + ip * 128 + tid;
            float tot = scr[tid] + scr[128 + tid] + scr[256 + tid] + scr[384 + tid];
            rho[pt] = exp2f(-sq[pt] * svh) * tot;
        }
    } else {
        #pragma unroll
        for (int m = 1; m < 64; m <<= 1) part += __shfl_xor(part, m);
        __syncthreads();
        double* dscr = (double*)scr;
        if (lane == 0) dscr[wid] = (double)part;
        __syncthreads();
        if (tid == 0) {
            double t = 0.0;
            #pragma unroll
            for (int w = 0; w < 8; ++w) t += dscr[w];
            off_part[b * 16 + ip] = t;
        }
    }
}

// ---------------------------------------------------------------- fused: invh (block 0) + g/dvs (block 1)
__global__ __launch_bounds__(256) void small_kernel(const double* __restrict__ op,
                                                    float* __restrict__ invh,
                                                    float* __restrict__ g,
                                                    float* __restrict__ dvs) {
    int tid = threadIdx.x;
    if (blockIdx.x == 0) {
        int b = tid >> 4, k = tid & 15;
        double v = op[b * 16 + k];
        #pragma unroll
        for (int m = 1; m < 16; m <<= 1) v += __shfl_xor(v, m);
        if (k == 0) {
            double h = v / ((double)M_ * (double)(M_ - 1));
            h = h > 1e-6 ? h : 1e-6;
            invh[b] = (float)(1.0 / (2.0 * h * h));
        }
    } else {
        __shared__ double w[256];
        double loc = 0.0;
        #pragma unroll
        for (int q = 0; q < 8; ++q) loc += 1.0 / (double)(M_ - (tid * 8 + q));
        w[tid] = loc; __syncthreads();
        for (int o = 1; o < 256; o <<= 1) {
            double v = (tid >= o) ? w[tid - o] : 0.0;
            __syncthreads();
            w[tid] += v;
            __syncthreads();
        }
        double acc = (tid > 0) ? w[tid - 1] : 0.0;
        #pragma unroll
        for (int q = 0; q < 8; ++q) {
            int t = tid * 8 + q;
            acc += 1.0 / (double)(M_ - t);
            g[t]   = (float)acc;
            dvs[t] = (float)(1.0 / sqrt((double)(t + 1)));
        }
    }
}

// ---------------------------------------------------------------- rank + scatter permutation
__global__ __launch_bounds__(128) void rank_kernel(const float* __restrict__ rho,
                                                   int* __restrict__ perm) {
    int b = blockIdx.y;
    int i = blockIdx.x * 128 + threadIdx.x;
    __shared__ float r[M_];
    const float* rb = rho + b * M_;
    for (int t = threadIdx.x; t < M_; t += 128) r[t] = rb[t];
    __syncthreads();
    float rv = r[i];
    int cnt = 0;
    #pragma unroll 4
    for (int j = 0; j < M_; ++j) {
        float o = r[j];
        cnt += (o < rv || (o == rv && j < i)) ? 1 : 0;
    }
    perm[b * M_ + cnt] = i;
}

// ---------------------------------------------------------------- per-chunk partial sums (64-pt chunks)
__global__ __launch_bounds__(128) void scan_chunk(
    const float* __restrict__ x, const int* __restrict__ perm,
    const float* __restrict__ g, const float* __restrict__ dvs,
    double* __restrict__ chunkU, double* __restrict__ chunkGU) {
    int b = blockIdx.x, ch = blockIdx.y, c = threadIdx.x;
    __shared__ int   pidx[64];
    __shared__ float gl[64], dl[64];
    int t0 = ch * 64;
    if (c < 64) {
        pidx[c] = perm[b * M_ + t0 + c];
        gl[c]   = g[t0 + c];
        dl[c]   = dvs[t0 + c];
    }
    __syncthreads();
    const float* xb = x + (size_t)b * M_ * C_;
    double sU = 0.0, sGU = 0.0;
    #pragma unroll 4
    for (int tt = 0; tt < 64; ++tt) {
        double u = (double)xb[(size_t)pidx[tt] * C_ + c] * (double)dl[tt];
        sU  += u;
        sGU += (double)gl[tt] * u;
    }
    chunkU [(size_t)(b * 32 + ch) * 128 + c] = sU;
    chunkGU[(size_t)(b * 32 + ch) * 128 + c] = sGU;
}

// ---------------------------------------------------------------- y via two prefix scans
__global__ __launch_bounds__(128) void scan_final(
    const float* __restrict__ x, const int* __restrict__ perm,
    const float* __restrict__ g, const float* __restrict__ dvs,
    const double* __restrict__ chunkU, const double* __restrict__ chunkGU,
    float* __restrict__ y) {
    int b = blockIdx.x, ch = blockIdx.y, c = threadIdx.x;
    __shared__ int   pidx[64];
    __shared__ float gl[64], dl[64];
    int t0 = ch * 64;
    if (c < 64) {
        pidx[c] = perm[b * M_ + t0 + c];
        gl[c]   = g[t0 + c];
        dl[c]   = dvs[t0 + c];
    }
    __syncthreads();
    double Utot = 0.0, runU = 0.0, runG = 0.0;
    #pragma unroll 4
    for (int q = 0; q < 32; ++q) {
        double cu = chunkU[(size_t)(b * 32 + q) * 128 + c];
        Utot += cu;
        if (q < ch) { runU += cu; runG += chunkGU[(size_t)(b * 32 + q) * 128 + c]; }
    }
    const float* xb = x + (size_t)b * M_ * C_;
    float*       yb = y + (size_t)b * M_ * C_;
    #pragma unroll 2
    for (int tt = 0; tt < 64; ++tt) {
        int idx = pidx[tt];
        double u  = (double)xb[(size_t)idx * C_ + c] * (double)dl[tt];
        double yv = (double)dl[tt] * ((double)gl[tt] * (Utot - runU) + runG);
        yb[(size_t)idx * C_ + c] = (float)yv;
        runU += u;
        runG += (double)gl[tt] * u;
    }
}

// ---------------------------------------------------------------- out = SiLU(y @ W^T), in-place
__global__ __launch_bounds__(256, 2) void linear_silu(float* __restrict__ y,
                                                      const float* __restrict__ W) {
    int b = blockIdx.y, m0 = blockIdx.x * 64;
    __shared__ f4 Y4[64][32];
    __shared__ f4 W4[64][32];
    float* yb = y + ((size_t)b * M_ + m0) * C_;
    int tid = threadIdx.x;
    for (int s = tid; s < 64 * 32; s += 256) {
        int row = s >> 5, c4 = s & 31;
        Y4[row][c4 ^ (row & 31)] = ((const f4*)(yb + (size_t)row * C_))[c4];
    }
    int tx = tid & 15, ty = tid >> 4;
    for (int half = 0; half < 2; ++half) {
        __syncthreads();
        for (int s = tid; s < 64 * 32; s += 256) {
            int row = s >> 5, c4 = s & 31;
            W4[row][c4 ^ (row & 31)] = ((const f4*)(W + (size_t)(half * 64 + row) * C_))[c4];
        }
        __syncthreads();
        float acc[4][4] = {};
        #pragma unroll 4
        for (int k4 = 0; k4 < 32; ++k4) {
            f4 a[4], w[4];
            #pragma unroll
            for (int d = 0; d < 4; ++d) {
                int rm = ty + 16 * d;
                a[d] = Y4[rm][k4 ^ (rm & 31)];
                int rc = tx + 16 * d;
                w[d] = W4[rc][k4 ^ (rc & 31)];
            }
            #pragma unroll
            for (int di = 0; di < 4; ++di)
                #pragma unroll
                for (int dj = 0; dj < 4; ++dj)
                    acc[di][dj] += a[di].x * w[dj].x + a[di].y * w[dj].y +
                                   a[di].z * w[dj].z + a[di].w * w[dj].w;
        }
        #pragma unroll
        for (int di = 0; di < 4; ++di)
            #pragma unroll
            for (int dj = 0; dj < 4; ++dj) {
                int m = ty + 16 * di, co = half * 64 + tx + 16 * dj;
                float v = acc[di][dj];
                yb[(size_t)m * C_ + co] = v / (1.f + __expf(-v));
            }
    }
}

// ----------------------------------------------------------------
extern "C" void kernel_launch(void* const* d_in, const int* in_sizes, int n_in,
                              void* d_out, int out_size, void* d_ws, size_t ws_size,
                              hipStream_t stream) {
    (void)in_sizes; (void)n_in; (void)out_size; (void)ws_size;
    const float* x = (const float*)d_in[0];
    const float* W = (const float*)d_in[1];
    float* out = (float*)d_out;

    char* ws = (char*)d_ws;
    size_t o = 0;
    auto alloc = [&](size_t n) { size_t r = o; o += (n + 255) & ~(size_t)255; return r; };
    double* off_part = (double*)(ws + alloc((size_t)B_ * 16 * 8));
    float*  invh     = (float*) (ws + alloc(B_ * 4));
    float*  sqv      = (float*) (ws + alloc((size_t)B_ * M_ * 4));        // 128KB
    float*  rho      = (float*) (ws + alloc((size_t)B_ * M_ * 4));        // 128KB
    int*    perm     = (int*)   (ws + alloc((size_t)B_ * M_ * 4));        // 128KB
    float*  g        = (float*) (ws + alloc(M_ * 4));
    float*  dvs      = (float*) (ws + alloc(M_ * 4));
    double* chunkU   = (double*)(ws + alloc((size_t)B_ * 32 * C_ * 8));   // 512KB
    double* chunkGU  = (double*)(ws + alloc((size_t)B_ * 32 * C_ * 8));   // 512KB
    // xhi bf16 (8MB) lives in d_out; consumed by grams before y is written.
    char* xhi = (char*)d_out;

    prep_kernel<<<(B_ * M_) / 8, 256, 0, stream>>>(x, (uint2*)xhi, sqv);
    gram_mfma<0><<<256, 512, 0, stream>>>(xhi, sqv, nullptr, off_part, nullptr);
    small_kernel<<<2, 256, 0, stream>>>(off_part, invh, g, dvs);
    gram_mfma<1><<<256, 512, 0, stream>>>(xhi, sqv, invh, nullptr, rho);
    rank_kernel<<<dim3(M_ / 128, B_), 128, 0, stream>>>(rho, perm);
    scan_chunk<<<dim3(B_, 32), 128, 0, stream>>>(x, perm, g, dvs, chunkU, chunkGU);
    scan_final<<<dim3(B_, 32), 128, 0, stream>>>(x, perm, g, dvs, chunkU, chunkGU, out);
    linear_silu<<<dim3(M_ / 64, B_), 256, 0, stream>>>(out, W);
}